// Round 4
// baseline (234.804 us; speedup 1.0000x reference)
//
#include <hip/hip_runtime.h>
#include <hip/hip_bf16.h>
#include <stdint.h>

#define B_   4
#define C_   768
#define T_   2048
#define H_   12
#define D_   64
#define O3_  2304

typedef __attribute__((ext_vector_type(4))) float f32x4;
typedef __attribute__((ext_vector_type(8))) short bf16x8;

__device__ __forceinline__ unsigned short f2bf(float f) {
  union { float f; unsigned int u; } v; v.f = f;
  unsigned int r = v.u + 0x7fffu + ((v.u >> 16) & 1u);
  return (unsigned short)(r >> 16);
}

__device__ __forceinline__ unsigned int pack2bf(float a, float b) {
  __hip_bfloat162 h2 = __float22bfloat162_rn(make_float2(a, b));
  union { __hip_bfloat162 h; unsigned int u; } cv; cv.h = h2;
  return cv.u;
}

__device__ __forceinline__ float fexp2(float x) {
#if __has_builtin(__builtin_amdgcn_exp2f)
  return __builtin_amdgcn_exp2f(x);
#else
  return exp2f(x);
#endif
}

// async global->LDS, 16B per lane; LDS dest = wave-uniform base + lane*16.
__device__ __forceinline__ void async16(const void* g, void* lds) {
#if __has_builtin(__builtin_amdgcn_global_load_lds)
  __builtin_amdgcn_global_load_lds((const __attribute__((address_space(1))) void*)g,
                                   (__attribute__((address_space(3))) void*)lds, 16, 0, 0);
#else
  int lane = threadIdx.x & 63;
  *((uint4*)((char*)lds + lane * 16)) = *((const uint4*)g);
#endif
}

// ---------------------------------------------------------------- prep kernels

__global__ void cvt_f32_bf16(const float* __restrict__ in,
                             unsigned short* __restrict__ out, int n4) {
  int i = blockIdx.x * 256 + threadIdx.x;
  if (i < n4) {
    float4 f = ((const float4*)in)[i];
    ushort4 o;
    o.x = f2bf(f.x); o.y = f2bf(f.y); o.z = f2bf(f.z); o.w = f2bf(f.w);
    ((ushort4*)out)[i] = o;
  }
}

// mask (B,1,1,T) int -> additive bias in exp2 domain
__global__ void make_bias(const int* __restrict__ mask, float* __restrict__ mbias, int n) {
  int i = blockIdx.x * 256 + threadIdx.x;
  if (i < n) mbias[i] = (mask[i] == 0) ? -14426.950408f : 0.0f;
}

// x[b][c][t] fp32 -> xT[b][t][c] bf16
__global__ void transpose_x(const float* __restrict__ x,
                            unsigned short* __restrict__ xT) {
  __shared__ unsigned short tile[32][33];
  int b = blockIdx.z;
  int c0 = blockIdx.y * 32;
  int t0 = blockIdx.x * 32;
  int tid = threadIdx.x;
  {
    int cl = tid >> 3;
    int tl = (tid & 7) * 4;
    float4 f = *(const float4*)(x + ((size_t)b * C_ + c0 + cl) * T_ + t0 + tl);
    tile[tl + 0][cl] = f2bf(f.x);
    tile[tl + 1][cl] = f2bf(f.y);
    tile[tl + 2][cl] = f2bf(f.z);
    tile[tl + 3][cl] = f2bf(f.w);
  }
  __syncthreads();
  {
    int tl = tid >> 3;
    int cl = (tid & 7) * 4;
    ushort4 o;
    o.x = tile[tl][cl + 0]; o.y = tile[tl][cl + 1];
    o.z = tile[tl][cl + 2]; o.w = tile[tl][cl + 3];
    *(ushort4*)(xT + ((size_t)b * T_ + t0 + tl) * C_ + c0 + cl) = o;
  }
}

// ---------------------------------------------------------------- QKV GEMM
// Epilogue layouts for attn:
//   Qb[bh][t][dd]                      (prescaled by 0.125*log2e)
//   Kb[bh][s][dd]   rows 64 shorts, 16B chunk c=dd>>3 stored at c^(s&7)
//   Vb[bh][tile][dd][64]  64-s tiles, chunk c=si>>3 stored at c^(dd&7)
__global__ __launch_bounds__(256)
void gemm_qkv(const unsigned short* __restrict__ xT,
              const unsigned short* __restrict__ W1,
              const float* __restrict__ bqkv,
              unsigned short* __restrict__ Qb,
              unsigned short* __restrict__ Kb,
              unsigned short* __restrict__ Vb) {
  __shared__ unsigned short sA[2][128 * 32];
  __shared__ unsigned short sB[2][128 * 32];

  const int b   = blockIdx.z;
  const int o0  = blockIdx.y * 128;
  const int t0  = blockIdx.x * 128;
  const int tid = threadIdx.x;
  const int wave = tid >> 6, lane = tid & 63;
  const int q = lane >> 4, ln = lane & 15;
  const int tw = wave >> 1, ow = wave & 1;

  const unsigned short* Ax = xT + (size_t)b * T_ * C_;
  const int srow = lane >> 2;
  const int scol = (lane & 3) * 8;

  const f32x4 ZERO = {0.f, 0.f, 0.f, 0.f};
  f32x4 acc[4][4];
#pragma unroll
  for (int mi = 0; mi < 4; ++mi)
#pragma unroll
    for (int ni = 0; ni < 4; ++ni) acc[mi][ni] = ZERO;

#pragma unroll
  for (int j = 0; j < 2; ++j) {
    const int chunk = wave * 2 + j;
    const int row = chunk * 16 + srow;
    async16(Ax + (size_t)(t0 + row) * C_ + scol, &sA[0][chunk * 512]);
    async16(W1 + (size_t)(o0 + row) * C_ + scol, &sB[0][chunk * 512]);
  }

  for (int i = 0; i < 24; ++i) {
    const int buf = i & 1;
    __syncthreads();
    if (i < 23) {
      const int k0 = (i + 1) * 32;
#pragma unroll
      for (int j = 0; j < 2; ++j) {
        const int chunk = wave * 2 + j;
        const int row = chunk * 16 + srow;
        async16(Ax + (size_t)(t0 + row) * C_ + k0 + scol, &sA[buf ^ 1][chunk * 512]);
        async16(W1 + (size_t)(o0 + row) * C_ + k0 + scol, &sB[buf ^ 1][chunk * 512]);
      }
    }

    bf16x8 aF[4], bF[4];
#pragma unroll
    for (int mi = 0; mi < 4; ++mi)
      aF[mi] = *(const bf16x8*)(&sA[buf][(tw * 64 + mi * 16 + ln) * 32 + q * 8]);
#pragma unroll
    for (int ni = 0; ni < 4; ++ni)
      bF[ni] = *(const bf16x8*)(&sB[buf][(ow * 64 + ni * 16 + ln) * 32 + q * 8]);
#pragma unroll
    for (int mi = 0; mi < 4; ++mi)
#pragma unroll
      for (int ni = 0; ni < 4; ++ni)
        acc[mi][ni] = __builtin_amdgcn_mfma_f32_16x16x32_bf16(aF[mi], bF[ni], acc[mi][ni], 0, 0, 0);
  }

  const float QSCL = 0.125f * 1.44269504f;
#pragma unroll
  for (int ni = 0; ni < 4; ++ni) {
    const int o = o0 + ow * 64 + ni * 16 + ln;
    const float bias = bqkv[o];
    const int which = o / C_;          // uniform per block (768 % 128 == 0)
    const int rem = o - which * C_;
    const int bh = b * H_ + (rem >> 6);
    const int dd = rem & 63;
#pragma unroll
    for (int mi = 0; mi < 4; ++mi) {
      const int tb = t0 + tw * 64 + mi * 16 + q * 4;
      f32x4 v = acc[mi][ni];
      if (which == 0) {
#pragma unroll
        for (int r = 0; r < 4; ++r)
          Qb[((size_t)bh * T_ + tb + r) * D_ + dd] = f2bf((v[r] + bias) * QSCL);
      } else if (which == 1) {
#pragma unroll
        for (int r = 0; r < 4; ++r) {
          const int s = tb + r;
          const int cp = (dd >> 3) ^ (s & 7);
          Kb[((size_t)bh * T_ + s) * 64 + (cp << 3) + (dd & 7)] = f2bf(v[r] + bias);
        }
      } else {
        const int tile = tb >> 6, si = tb & 63;
        const int cp = (si >> 3) ^ (dd & 7);
        ushort4 pk;
        pk.x = f2bf(v[0] + bias);
        pk.y = f2bf(v[1] + bias);
        pk.z = f2bf(v[2] + bias);
        pk.w = f2bf(v[3] + bias);
        *(ushort4*)(Vb + (((size_t)bh * 32 + tile) * 64 + dd) * 64 + (cp << 3) + (si & 7)) = pk;
      }
    }
  }
}

// ---------------------------------------------------------------- attention
// Fixed-max flash (Q prescaled to exp2 domain). One block = (bh, 128 t),
// 8 waves of an in-tile s-split: wave (si = w>>2, wj = w&3) owns 32 t-cols
// (wj) x the si-half (32 s) of every shared 64-s K/V tile. Staging/tiles/
// swizzles identical to the verified 4-wave version (8 chunks/tile, 1 per
// wave); per-wave work halves (kc collapses to kc=si); LDS 35328B so all
// 768 blocks co-resident: 3 blocks/CU = 24 waves/CU (6/SIMD).
// P stays in registers via permlane32+permlane16 swaps. T15 pipeline:
// body it: stage K(it+2),V(it+1); QK(it+1) || PV(it). End: si=0/1 partials
// combined via the round-0-verified padded LDS combine (stride-68 fbuf).
__global__ __launch_bounds__(512, 4)
void attn(const unsigned short* __restrict__ Qb,
          const unsigned short* __restrict__ Kb,
          const unsigned short* __restrict__ Vb,
          const float* __restrict__ mbias,
          unsigned short* __restrict__ Ob) {
  __shared__ __align__(16) char smem[35328];
  // [0,16K): sK dbuf (2x8KB); [16K,32K): sV dbuf
  // combine reuses [0,34816) as fbuf (128 rows x stride 68 f32) + lbuf
  unsigned short* sK0 = (unsigned short*)smem;             // + parity*4096
  unsigned short* sV0 = (unsigned short*)(smem + 16384);   // + parity*4096

  const int id = blockIdx.x;                  // id = bh + 48*tblk -> XCD = bh%8
  const int bh = id % 48;
  const int tblk = id / 48;
  const int b = bh / H_, h = bh % H_;
  const int tid = threadIdx.x, wave = tid >> 6, lane = tid & 63;
  const int q = lane >> 4, ln = lane & 15;
  const int wj = wave & 3, si = wave >> 2;    // t-quarter, s-half
  const int t0w = tblk * 128 + wj * 32;       // this wave's 32 t-cols

  // Q fragments (B-operand): [tt][kk], t = t0w + tt*16 + ln, k = kk*32+q*8
  bf16x8 Qa[2][2];
#pragma unroll
  for (int tt = 0; tt < 2; ++tt) {
    const unsigned short* qrow = Qb + ((size_t)bh * T_ + t0w + tt * 16 + ln) * D_;
    Qa[tt][0] = *(const bf16x8*)(qrow + q * 8);
    Qa[tt][1] = *(const bf16x8*)(qrow + 32 + q * 8);
  }

  const f32x4 ZERO = {0.f, 0.f, 0.f, 0.f};
  f32x4 Oacc[4][2];   // [dt][tt], O^T C-layout: row=d, col=t (partial over si)
  f32x4 lacc[2];      // [tt], row0 = partial l
#pragma unroll
  for (int dt = 0; dt < 4; ++dt)
#pragma unroll
    for (int tt = 0; tt < 2; ++tt) Oacc[dt][tt] = ZERO;
#pragma unroll
  for (int tt = 0; tt < 2; ++tt) lacc[tt] = ZERO;

  const short one_s = (ln == 0) ? (short)0x3F80 : (short)0;
  bf16x8 ones;
#pragma unroll
  for (int j = 0; j < 8; ++j) ones[j] = one_s;

  const unsigned short* gK = Kb + (size_t)bh * T_ * 64;
  const unsigned short* gV = Vb + (size_t)bh * 32 * 4096;
  const float* mb = mbias + b * T_;

  // stage one 8KB tile: 8 chunks of 1KB, chunk `wave` handled by this wave
  auto stage1 = [&](const unsigned short* g, unsigned short* lds) {
    async16(g + wave * 512 + lane * 8, lds + wave * 512);
  };

  // QK^T for this wave's 32-s half of one tile; emits P B-fragments
  // (s_rel = q*8 + j within the si-half, t = ln)
  auto QK = [&](const unsigned short* sKc, int s0, bf16x8 pfO[2]) {
    const float bvl = mb[s0 + si * 32 + (lane & 31)];
    const bool anymask = (__ballot(bvl != 0.0f) != 0ull);
    bf16x8 kf0[2], kf1[2];
#pragma unroll
    for (int sb = 0; sb < 2; ++sb) {
      const unsigned short* krow = sKc + (si * 32 + sb * 16 + ln) * 64;
      kf0[sb] = *(const bf16x8*)(krow + ((q ^ (ln & 7)) << 3));
      kf1[sb] = *(const bf16x8*)(krow + (((4 + q) ^ (ln & 7)) << 3));
    }
#pragma unroll
    for (int tt = 0; tt < 2; ++tt) {
      f32x4 sc[2];
#pragma unroll
      for (int sb = 0; sb < 2; ++sb) {
        f32x4 p0 = __builtin_amdgcn_mfma_f32_16x16x32_bf16(kf0[sb], Qa[tt][0], ZERO, 0, 0, 0);
        sc[sb]   = __builtin_amdgcn_mfma_f32_16x16x32_bf16(kf1[sb], Qa[tt][1], p0, 0, 0, 0);
        if (anymask) {
          f32x4 bb = *(const f32x4*)(mb + s0 + si * 32 + sb * 16 + q * 4);
#pragma unroll
          for (int r = 0; r < 4; ++r) sc[sb][r] += bb[r];
        }
      }
      unsigned int A0 = pack2bf(fexp2(sc[0][0]), fexp2(sc[0][1]));
      unsigned int B0 = pack2bf(fexp2(sc[0][2]), fexp2(sc[0][3]));
      unsigned int C0 = pack2bf(fexp2(sc[1][0]), fexp2(sc[1][1]));
      unsigned int E0 = pack2bf(fexp2(sc[1][2]), fexp2(sc[1][3]));
      // swap network: (A0,C0) -> (T0,T2), (B0,E0) -> (T1,T3)
      asm volatile("v_permlane32_swap_b32 %0, %1" : "+v"(A0), "+v"(C0));
      asm volatile("v_permlane16_swap_b32 %0, %1" : "+v"(A0), "+v"(C0));
      asm volatile("v_permlane32_swap_b32 %0, %1" : "+v"(B0), "+v"(E0));
      asm volatile("v_permlane16_swap_b32 %0, %1" : "+v"(B0), "+v"(E0));
      union { bf16x8 v; unsigned int u[4]; } P;
      P.u[0] = A0;  // s_rel = q*8 + {0,1}
      P.u[1] = B0;  // s_rel = q*8 + {2,3}
      P.u[2] = C0;  // s_rel = q*8 + {4,5}
      P.u[3] = E0;  // s_rel = q*8 + {6,7}
      pfO[tt] = P.v;
    }
  };

  // PV for this wave's 32-s half using prepared P-fragments
  auto PV = [&](const unsigned short* sVc, bf16x8 pfI[2]) {
#pragma unroll
    for (int dt = 0; dt < 4; ++dt) {
      bf16x8 vf = *(const bf16x8*)(sVc + (dt * 16 + ln) * 64 +
                                   (((si * 4 + q) ^ (ln & 7)) << 3));
#pragma unroll
      for (int tt = 0; tt < 2; ++tt)
        Oacc[dt][tt] = __builtin_amdgcn_mfma_f32_16x16x32_bf16(vf, pfI[tt], Oacc[dt][tt], 0, 0, 0);
    }
#pragma unroll
    for (int tt = 0; tt < 2; ++tt)
      lacc[tt] = __builtin_amdgcn_mfma_f32_16x16x32_bf16(ones, pfI[tt], lacc[tt], 0, 0, 0);
  };

  bf16x8 pfA[2], pfB[2];

  // prologue: K(0)->k0, V(0)->v0; after barrier stage K(1)->k1 and run QK(0)
  stage1(gK, sK0);
  stage1(gV, sV0);
  __syncthreads();
  stage1(gK + 4096, sK0 + 4096);
  QK(sK0, 0, pfA);

  // main loop: 15 double-bodies cover it = 0..29
  for (int ith = 0; ith < 15; ++ith) {
    const int it = ith * 2;
    // even body (parity 0): QK(it+1) || PV(it)
    __syncthreads();
    stage1(gK + (size_t)(it + 2) * 4096, sK0);          // K(it+2) -> k0
    stage1(gV + (size_t)(it + 1) * 4096, sV0 + 4096);   // V(it+1) -> v1
    QK(sK0 + 4096, (it + 1) * 64, pfB);
    PV(sV0, pfA);
    // odd body (parity 1): QK(it+2) || PV(it+1)
    __syncthreads();
    stage1(gK + (size_t)(it + 3) * 4096, sK0 + 4096);   // K(it+3) -> k1
    stage1(gV + (size_t)(it + 2) * 4096, sV0);          // V(it+2) -> v0
    QK(sK0, (it + 2) * 64, pfA);
    PV(sV0 + 4096, pfB);
  }

  // peeled tail: it = 30 (QK(31) || PV(30)), then it = 31 (PV only)
  __syncthreads();
  stage1(gV + (size_t)31 * 4096, sV0 + 4096);           // V(31) -> v1
  QK(sK0 + 4096, 31 * 64, pfB);                         // K(31) in k1
  PV(sV0, pfA);                                         // V(30) in v0
  __syncthreads();
  PV(sV0 + 4096, pfB);                                  // V(31) in v1

  // ---- combine si halves via padded LDS (round-0-verified), normalize, store
  __syncthreads();
  float* fbuf = (float*)smem;               // 128 rows x stride 68 f32
  float* lbuf = (float*)(smem + 34816);     // 128 f32
  if (si == 1) {
#pragma unroll
    for (int tt = 0; tt < 2; ++tt) {
      const int row = wj * 32 + tt * 16 + ln;
#pragma unroll
      for (int dt = 0; dt < 4; ++dt)
        *(f32x4*)(fbuf + (size_t)row * 68 + dt * 16 + q * 4) = Oacc[dt][tt];
      if (q == 0) lbuf[row] = lacc[tt][0];
    }
  }
  __syncthreads();
  if (si == 0) {
#pragma unroll
    for (int tt = 0; tt < 2; ++tt) {
      const int row = wj * 32 + tt * 16 + ln;
      const float lv = __shfl(lacc[tt][0], ln, 64) + lbuf[row];
      const float inv = 1.0f / lv;
      const int t = t0w + tt * 16 + ln;
#pragma unroll
      for (int dt = 0; dt < 4; ++dt) {
        f32x4 p = *(const f32x4*)(fbuf + (size_t)row * 68 + dt * 16 + q * 4);
        f32x4 o = Oacc[dt][tt];
        ushort4 pk;
        pk.x = f2bf((o[0] + p[0]) * inv);
        pk.y = f2bf((o[1] + p[1]) * inv);
        pk.z = f2bf((o[2] + p[2]) * inv);
        pk.w = f2bf((o[3] + p[3]) * inv);
        *(ushort4*)(Ob + ((size_t)b * T_ + t) * C_ + h * D_ + dt * 16 + q * 4) = pk;
      }
    }
  }
}

// ---------------------------------------------------------------- out GEMM
__global__ __launch_bounds__(256)
void gemm_out(const unsigned short* __restrict__ Ob,
              const unsigned short* __restrict__ W2,
              const float* __restrict__ bout,
              float* __restrict__ out) {
  __shared__ unsigned short sA[2][128 * 32];
  __shared__ unsigned short sB[2][128 * 32];

  const int b   = blockIdx.z;
  const int o0  = blockIdx.y * 128;
  const int t0  = blockIdx.x * 128;
  const int tid = threadIdx.x;
  const int wave = tid >> 6, lane = tid & 63;
  const int q = lane >> 4, ln = lane & 15;
  const int tw = wave >> 1, ow = wave & 1;

  const unsigned short* Bo = Ob + (size_t)b * T_ * C_;
  const int srow = lane >> 2;
  const int scol = (lane & 3) * 8;

  const f32x4 ZERO = {0.f, 0.f, 0.f, 0.f};
  f32x4 acc[4][4];
#pragma unroll
  for (int mi = 0; mi < 4; ++mi)
#pragma unroll
    for (int ni = 0; ni < 4; ++ni) acc[mi][ni] = ZERO;

#pragma unroll
  for (int j = 0; j < 2; ++j) {
    const int chunk = wave * 2 + j;
    const int row = chunk * 16 + srow;
    async16(W2 + (size_t)(o0 + row) * C_ + scol, &sA[0][chunk * 512]);
    async16(Bo + (size_t)(t0 + row) * C_ + scol, &sB[0][chunk * 512]);
  }

  for (int i = 0; i < 24; ++i) {
    const int buf = i & 1;
    __syncthreads();
    if (i < 23) {
      const int k0 = (i + 1) * 32;
#pragma unroll
      for (int j = 0; j < 2; ++j) {
        const int chunk = wave * 2 + j;
        const int row = chunk * 16 + srow;
        async16(W2 + (size_t)(o0 + row) * C_ + k0 + scol, &sA[buf ^ 1][chunk * 512]);
        async16(Bo + (size_t)(t0 + row) * C_ + k0 + scol, &sB[buf ^ 1][chunk * 512]);
      }
    }

    bf16x8 aF[4], bF[4];
#pragma unroll
    for (int mi = 0; mi < 4; ++mi)
      aF[mi] = *(const bf16x8*)(&sA[buf][(tw * 64 + mi * 16 + ln) * 32 + q * 8]);
#pragma unroll
    for (int ni = 0; ni < 4; ++ni)
      bF[ni] = *(const bf16x8*)(&sB[buf][(ow * 64 + ni * 16 + ln) * 32 + q * 8]);
#pragma unroll
    for (int mi = 0; mi < 4; ++mi)
#pragma unroll
      for (int ni = 0; ni < 4; ++ni)
        acc[mi][ni] = __builtin_amdgcn_mfma_f32_16x16x32_bf16(aF[mi], bF[ni], acc[mi][ni], 0, 0, 0);
  }

#pragma unroll
  for (int mi = 0; mi < 4; ++mi) {
    const int ob = o0 + tw * 64 + mi * 16 + q * 4;
#pragma unroll
    for (int ni = 0; ni < 4; ++ni) {
      const int t = t0 + ow * 64 + ni * 16 + ln;
      f32x4 v = acc[mi][ni];
#pragma unroll
      for (int r = 0; r < 4; ++r)
        out[((size_t)b * C_ + ob + r) * T_ + t] = v[r] + bout[ob + r];
    }
  }
}

// ---------------------------------------------------------------- launch

extern "C" void kernel_launch(void* const* d_in, const int* in_sizes, int n_in,
                              void* d_out, int out_size, void* d_ws, size_t ws_size,
                              hipStream_t stream) {
  (void)in_sizes; (void)n_in; (void)out_size; (void)ws_size;
  const float* x    = (const float*)d_in[0];
  const int*   mask = (const int*)d_in[1];
  const float* Wqkv = (const float*)d_in[2];
  const float* bqkv = (const float*)d_in[3];
  const float* Wout = (const float*)d_in[4];
  const float* bout = (const float*)d_in[5];
  float* out = (float*)d_out;

  const size_t szHead = (size_t)B_ * H_ * T_ * D_;   // 6291456 elems
  const size_t szBTC  = (size_t)B_ * T_ * C_;        // 6291456 elems
  unsigned short* Qb  = (unsigned short*)d_ws;
  unsigned short* Kb  = Qb + szHead;
  unsigned short* Vb  = Kb + szHead;
  unsigned short* Ob  = Vb + szHead;
  unsigned short* xT  = Ob + szBTC;
  unsigned short* W1b = xT + szBTC;
  unsigned short* W2b = W1b + (size_t)O3_ * C_;
  float* mbias        = (float*)(W2b + (size_t)C_ * C_);

  cvt_f32_bf16<<<dim3((O3_ * C_ / 4 + 255) / 256), 256, 0, stream>>>(Wqkv, W1b, O3_ * C_ / 4);
  cvt_f32_bf16<<<dim3((C_ * C_ / 4 + 255) / 256), 256, 0, stream>>>(Wout, W2b, C_ * C_ / 4);
  make_bias<<<dim3((B_ * T_ + 255) / 256), 256, 0, stream>>>(mask, mbias, B_ * T_);
  transpose_x<<<dim3(T_ / 32, C_ / 32, B_), 256, 0, stream>>>(x, xT);
  gemm_qkv<<<dim3(T_ / 128, O3_ / 128, B_), 256, 0, stream>>>(xT, W1b, bqkv, Qb, Kb, Vb);
  attn<<<dim3(768), 512, 0, stream>>>(Qb, Kb, Vb, mbias, Ob);
  gemm_out<<<dim3(T_ / 128, C_ / 128, B_), 256, 0, stream>>>(Ob, W2b, bout, out);
}

// Round 5
// 227.902 us; speedup vs baseline: 1.0303x; 1.0303x over previous
//
#include <hip/hip_runtime.h>
#include <hip/hip_bf16.h>
#include <stdint.h>

#define B_   4
#define C_   768
#define T_   2048
#define H_   12
#define D_   64
#define O3_  2304

typedef __attribute__((ext_vector_type(4))) float f32x4;
typedef __attribute__((ext_vector_type(8))) short bf16x8;

__device__ __forceinline__ unsigned short f2bf(float f) {
  union { float f; unsigned int u; } v; v.f = f;
  unsigned int r = v.u + 0x7fffu + ((v.u >> 16) & 1u);
  return (unsigned short)(r >> 16);
}

__device__ __forceinline__ unsigned int pack2bf(float a, float b) {
  __hip_bfloat162 h2 = __float22bfloat162_rn(make_float2(a, b));
  union { __hip_bfloat162 h; unsigned int u; } cv; cv.h = h2;
  return cv.u;
}

__device__ __forceinline__ float fexp2(float x) {
#if __has_builtin(__builtin_amdgcn_exp2f)
  return __builtin_amdgcn_exp2f(x);
#else
  return exp2f(x);
#endif
}

// async global->LDS, 16B per lane; LDS dest = wave-uniform base + lane*16.
__device__ __forceinline__ void async16(const void* g, void* lds) {
#if __has_builtin(__builtin_amdgcn_global_load_lds)
  __builtin_amdgcn_global_load_lds((const __attribute__((address_space(1))) void*)g,
                                   (__attribute__((address_space(3))) void*)lds, 16, 0, 0);
#else
  int lane = threadIdx.x & 63;
  *((uint4*)((char*)lds + lane * 16)) = *((const uint4*)g);
#endif
}

// ---------------------------------------------------------------- prep kernels

__global__ void cvt_f32_bf16(const float* __restrict__ in,
                             unsigned short* __restrict__ out, int n4) {
  int i = blockIdx.x * 256 + threadIdx.x;
  if (i < n4) {
    float4 f = ((const float4*)in)[i];
    ushort4 o;
    o.x = f2bf(f.x); o.y = f2bf(f.y); o.z = f2bf(f.z); o.w = f2bf(f.w);
    ((ushort4*)out)[i] = o;
  }
}

// mask (B,1,1,T) int -> additive bias in exp2 domain
__global__ void make_bias(const int* __restrict__ mask, float* __restrict__ mbias, int n) {
  int i = blockIdx.x * 256 + threadIdx.x;
  if (i < n) mbias[i] = (mask[i] == 0) ? -14426.950408f : 0.0f;
}

// x[b][c][t] fp32 -> xT[b][t][c] bf16
__global__ void transpose_x(const float* __restrict__ x,
                            unsigned short* __restrict__ xT) {
  __shared__ unsigned short tile[32][33];
  int b = blockIdx.z;
  int c0 = blockIdx.y * 32;
  int t0 = blockIdx.x * 32;
  int tid = threadIdx.x;
  {
    int cl = tid >> 3;
    int tl = (tid & 7) * 4;
    float4 f = *(const float4*)(x + ((size_t)b * C_ + c0 + cl) * T_ + t0 + tl);
    tile[tl + 0][cl] = f2bf(f.x);
    tile[tl + 1][cl] = f2bf(f.y);
    tile[tl + 2][cl] = f2bf(f.z);
    tile[tl + 3][cl] = f2bf(f.w);
  }
  __syncthreads();
  {
    int tl = tid >> 3;
    int cl = (tid & 7) * 4;
    ushort4 o;
    o.x = tile[tl][cl + 0]; o.y = tile[tl][cl + 1];
    o.z = tile[tl][cl + 2]; o.w = tile[tl][cl + 3];
    *(ushort4*)(xT + ((size_t)b * T_ + t0 + tl) * C_ + c0 + cl) = o;
  }
}

// ---------------------------------------------------------------- QKV GEMM
// Epilogue layouts for attn:
//   Qb[bh][t][dd]                      (prescaled by 0.125*log2e)
//   Kb[bh][s][dd]   rows 64 shorts, 16B chunk c=dd>>3 stored at c^(s&7)
//   Vb[bh][tile][dd][64]  64-s tiles, chunk c=si>>3 stored at c^(dd&7)
__global__ __launch_bounds__(256)
void gemm_qkv(const unsigned short* __restrict__ xT,
              const unsigned short* __restrict__ W1,
              const float* __restrict__ bqkv,
              unsigned short* __restrict__ Qb,
              unsigned short* __restrict__ Kb,
              unsigned short* __restrict__ Vb) {
  __shared__ unsigned short sA[2][128 * 32];
  __shared__ unsigned short sB[2][128 * 32];

  const int b   = blockIdx.z;
  const int o0  = blockIdx.y * 128;
  const int t0  = blockIdx.x * 128;
  const int tid = threadIdx.x;
  const int wave = tid >> 6, lane = tid & 63;
  const int q = lane >> 4, ln = lane & 15;
  const int tw = wave >> 1, ow = wave & 1;

  const unsigned short* Ax = xT + (size_t)b * T_ * C_;
  const int srow = lane >> 2;
  const int scol = (lane & 3) * 8;

  const f32x4 ZERO = {0.f, 0.f, 0.f, 0.f};
  f32x4 acc[4][4];
#pragma unroll
  for (int mi = 0; mi < 4; ++mi)
#pragma unroll
    for (int ni = 0; ni < 4; ++ni) acc[mi][ni] = ZERO;

#pragma unroll
  for (int j = 0; j < 2; ++j) {
    const int chunk = wave * 2 + j;
    const int row = chunk * 16 + srow;
    async16(Ax + (size_t)(t0 + row) * C_ + scol, &sA[0][chunk * 512]);
    async16(W1 + (size_t)(o0 + row) * C_ + scol, &sB[0][chunk * 512]);
  }

  for (int i = 0; i < 24; ++i) {
    const int buf = i & 1;
    __syncthreads();
    if (i < 23) {
      const int k0 = (i + 1) * 32;
#pragma unroll
      for (int j = 0; j < 2; ++j) {
        const int chunk = wave * 2 + j;
        const int row = chunk * 16 + srow;
        async16(Ax + (size_t)(t0 + row) * C_ + k0 + scol, &sA[buf ^ 1][chunk * 512]);
        async16(W1 + (size_t)(o0 + row) * C_ + k0 + scol, &sB[buf ^ 1][chunk * 512]);
      }
    }

    bf16x8 aF[4], bF[4];
#pragma unroll
    for (int mi = 0; mi < 4; ++mi)
      aF[mi] = *(const bf16x8*)(&sA[buf][(tw * 64 + mi * 16 + ln) * 32 + q * 8]);
#pragma unroll
    for (int ni = 0; ni < 4; ++ni)
      bF[ni] = *(const bf16x8*)(&sB[buf][(ow * 64 + ni * 16 + ln) * 32 + q * 8]);
#pragma unroll
    for (int mi = 0; mi < 4; ++mi)
#pragma unroll
      for (int ni = 0; ni < 4; ++ni)
        acc[mi][ni] = __builtin_amdgcn_mfma_f32_16x16x32_bf16(aF[mi], bF[ni], acc[mi][ni], 0, 0, 0);
  }

  const float QSCL = 0.125f * 1.44269504f;
#pragma unroll
  for (int ni = 0; ni < 4; ++ni) {
    const int o = o0 + ow * 64 + ni * 16 + ln;
    const float bias = bqkv[o];
    const int which = o / C_;          // uniform per block (768 % 128 == 0)
    const int rem = o - which * C_;
    const int bh = b * H_ + (rem >> 6);
    const int dd = rem & 63;
#pragma unroll
    for (int mi = 0; mi < 4; ++mi) {
      const int tb = t0 + tw * 64 + mi * 16 + q * 4;
      f32x4 v = acc[mi][ni];
      if (which == 0) {
#pragma unroll
        for (int r = 0; r < 4; ++r)
          Qb[((size_t)bh * T_ + tb + r) * D_ + dd] = f2bf((v[r] + bias) * QSCL);
      } else if (which == 1) {
#pragma unroll
        for (int r = 0; r < 4; ++r) {
          const int s = tb + r;
          const int cp = (dd >> 3) ^ (s & 7);
          Kb[((size_t)bh * T_ + s) * 64 + (cp << 3) + (dd & 7)] = f2bf(v[r] + bias);
        }
      } else {
        const int tile = tb >> 6, si = tb & 63;
        const int cp = (si >> 3) ^ (dd & 7);
        ushort4 pk;
        pk.x = f2bf(v[0] + bias);
        pk.y = f2bf(v[1] + bias);
        pk.z = f2bf(v[2] + bias);
        pk.w = f2bf(v[3] + bias);
        *(ushort4*)(Vb + (((size_t)bh * 32 + tile) * 64 + dd) * 64 + (cp << 3) + (si & 7)) = pk;
      }
    }
  }
}

// ---------------------------------------------------------------- attention
// Fixed-max flash (Q prescaled to exp2 domain). One block = (bh, 128 t),
// 4 waves; each wave owns 32 t-cols x FULL s-range (verified r2 structure).
// P stays in registers via permlane32+permlane16 swaps.
//
// T4 counted-vmcnt pipeline: K and V triple-buffered (3 x 8KB each),
// prefetch depth 2 (body it stages tile it+2). Body boundary =
//   sched_barrier(0); s_waitcnt vmcnt(4) lgkmcnt(0); s_barrier; sched_barrier(0)
// -> the 4 loads issued THIS body stay in flight across the barrier; only
// the tile-it loads (issued 2 bodies ago) must be complete. Never vmcnt(0)
// in the main loop. mbias is pre-collapsed to a 32-bit maskbits register
// before the loop so NO vmem op occurs inside a body except the 4 stages
// (a global load inside the body would force a compiler drain and defeat
// the counted wait).
__global__ __launch_bounds__(256, 3)
void attn(const unsigned short* __restrict__ Qb,
          const unsigned short* __restrict__ Kb,
          const unsigned short* __restrict__ Vb,
          const float* __restrict__ mbias,
          unsigned short* __restrict__ Ob) {
  __shared__ __align__(16) char smem[49152];
  // [0,24K): sK 3 x 8KB; [24K,48K): sV 3 x 8KB
  unsigned short* sK0 = (unsigned short*)smem;             // + buf*4096 shorts
  unsigned short* sV0 = (unsigned short*)(smem + 24576);

  const int id = blockIdx.x;                  // id = bh + 48*tblk -> XCD = bh%8
  const int bh = id % 48;
  const int tblk = id / 48;
  const int b = bh / H_, h = bh % H_;
  const int tid = threadIdx.x, wave = tid >> 6, lane = tid & 63;
  const int q = lane >> 4, ln = lane & 15;
  const int t0w = tblk * 128 + wave * 32;     // this wave's 32 t-cols

  // Q fragments (B-operand): [tt][kk], t = t0w + tt*16 + ln, k = kk*32+q*8
  bf16x8 Qa[2][2];
#pragma unroll
  for (int tt = 0; tt < 2; ++tt) {
    const unsigned short* qrow = Qb + ((size_t)bh * T_ + t0w + tt * 16 + ln) * D_;
    Qa[tt][0] = *(const bf16x8*)(qrow + q * 8);
    Qa[tt][1] = *(const bf16x8*)(qrow + 32 + q * 8);
  }

  const f32x4 ZERO = {0.f, 0.f, 0.f, 0.f};
  f32x4 Oacc[4][2];   // [dt][tt], O^T C-layout: row=d, col=t
  f32x4 lacc[2];      // [tt], row0 = l
#pragma unroll
  for (int dt = 0; dt < 4; ++dt)
#pragma unroll
    for (int tt = 0; tt < 2; ++tt) Oacc[dt][tt] = ZERO;
#pragma unroll
  for (int tt = 0; tt < 2; ++tt) lacc[tt] = ZERO;

  const short one_s = (ln == 0) ? (short)0x3F80 : (short)0;
  bf16x8 ones;
#pragma unroll
  for (int j = 0; j < 8; ++j) ones[j] = one_s;

  const unsigned short* gK = Kb + (size_t)bh * T_ * 64;
  const unsigned short* gV = Vb + (size_t)bh * 32 * 4096;
  const float* mb = mbias + b * T_;

  // pre-collapse mask to one bit per 64-s tile (no vmem inside the hot loop)
  unsigned int maskbits = 0;
  for (int t2 = 0; t2 < 32; ++t2)
    if (__ballot(mb[t2 * 64 + lane] != 0.0f) != 0ull) maskbits |= (1u << t2);

  // stage one 8KB tile (64 rows x 64 shorts): 8 chunks of 1KB, 2 per wave
  auto stage = [&](const unsigned short* g, unsigned short* lds) {
#pragma unroll
    for (int j = 0; j < 2; ++j) {
      const int chunk = wave * 2 + j;
      async16(g + chunk * 512 + lane * 8, lds + chunk * 512);
    }
  };

  // body boundary: only the 4 newest loads (this body's stages) may remain
  // in flight; tile-it loads (2 bodies old) are forced complete.
  auto sync4 = [&]() {
    __builtin_amdgcn_sched_barrier(0);
    asm volatile("s_waitcnt vmcnt(4) lgkmcnt(0)" ::: "memory");
    __builtin_amdgcn_s_barrier();
    __builtin_amdgcn_sched_barrier(0);
  };
  auto sync0 = [&]() {
    __builtin_amdgcn_sched_barrier(0);
    asm volatile("s_waitcnt vmcnt(0) lgkmcnt(0)" ::: "memory");
    __builtin_amdgcn_s_barrier();
    __builtin_amdgcn_sched_barrier(0);
  };

  // QK^T for one 64-s tile; emits P B-fragments (s = kc*32 + q*8 + j, t = ln)
  auto QK = [&](const unsigned short* sKc, int it, bf16x8 pfO[2][2]) {
    const int s0 = it * 64;
    const bool anymask = (maskbits >> it) & 1;
#pragma unroll
    for (int kc = 0; kc < 2; ++kc) {
      bf16x8 kf0[2], kf1[2];
#pragma unroll
      for (int sb = 0; sb < 2; ++sb) {
        const unsigned short* krow = sKc + (kc * 32 + sb * 16 + ln) * 64;
        kf0[sb] = *(const bf16x8*)(krow + ((q ^ (ln & 7)) << 3));
        kf1[sb] = *(const bf16x8*)(krow + (((4 + q) ^ (ln & 7)) << 3));
      }
#pragma unroll
      for (int tt = 0; tt < 2; ++tt) {
        f32x4 sc[2];
#pragma unroll
        for (int sb = 0; sb < 2; ++sb) {
          f32x4 p0 = __builtin_amdgcn_mfma_f32_16x16x32_bf16(kf0[sb], Qa[tt][0], ZERO, 0, 0, 0);
          sc[sb]   = __builtin_amdgcn_mfma_f32_16x16x32_bf16(kf1[sb], Qa[tt][1], p0, 0, 0, 0);
          if (anymask) {
            f32x4 bb = *(const f32x4*)(mb + s0 + kc * 32 + sb * 16 + q * 4);
#pragma unroll
            for (int r = 0; r < 4; ++r) sc[sb][r] += bb[r];
          }
        }
        unsigned int A0 = pack2bf(fexp2(sc[0][0]), fexp2(sc[0][1]));
        unsigned int B0 = pack2bf(fexp2(sc[0][2]), fexp2(sc[0][3]));
        unsigned int C0 = pack2bf(fexp2(sc[1][0]), fexp2(sc[1][1]));
        unsigned int E0 = pack2bf(fexp2(sc[1][2]), fexp2(sc[1][3]));
        // swap network: (A0,C0) -> (T0,T2), (B0,E0) -> (T1,T3)
        asm volatile("v_permlane32_swap_b32 %0, %1" : "+v"(A0), "+v"(C0));
        asm volatile("v_permlane16_swap_b32 %0, %1" : "+v"(A0), "+v"(C0));
        asm volatile("v_permlane32_swap_b32 %0, %1" : "+v"(B0), "+v"(E0));
        asm volatile("v_permlane16_swap_b32 %0, %1" : "+v"(B0), "+v"(E0));
        union { bf16x8 v; unsigned int u[4]; } P;
        P.u[0] = A0;  // s = q*8 + {0,1}
        P.u[1] = B0;  // s = q*8 + {2,3}
        P.u[2] = C0;  // s = q*8 + {4,5}
        P.u[3] = E0;  // s = q*8 + {6,7}
        pfO[tt][kc] = P.v;
      }
    }
  };

  // PV for one 64-s tile using prepared P-fragments
  auto PV = [&](const unsigned short* sVc, bf16x8 pfI[2][2]) {
#pragma unroll
    for (int dt = 0; dt < 4; ++dt) {
#pragma unroll
      for (int kc = 0; kc < 2; ++kc) {
        bf16x8 vf = *(const bf16x8*)(sVc + (dt * 16 + ln) * 64 +
                                     (((kc * 4 + q) ^ (ln & 7)) << 3));
#pragma unroll
        for (int tt = 0; tt < 2; ++tt)
          Oacc[dt][tt] = __builtin_amdgcn_mfma_f32_16x16x32_bf16(vf, pfI[tt][kc], Oacc[dt][tt], 0, 0, 0);
      }
    }
#pragma unroll
    for (int kc = 0; kc < 2; ++kc)
#pragma unroll
      for (int tt = 0; tt < 2; ++tt)
        lacc[tt] = __builtin_amdgcn_mfma_f32_16x16x32_bf16(ones, pfI[tt][kc], lacc[tt], 0, 0, 0);
  };

  bf16x8 pf[2][2];

  // prologue: stage tiles 0 and 1 (8 loads outstanding per wave)
  stage(gK, sK0);
  stage(gV, sV0);
  stage(gK + 4096, sK0 + 4096);
  stage(gV + 4096, sV0 + 4096);

  // main loop: 10 triple-bodies cover it = 0..29; buffer index = it%3 static
  for (int ith = 0; ith < 10; ++ith) {
    const int it = ith * 3;
    // body it (buf 0), stage tile it+2 -> buf 2
    sync4();
    stage(gK + (size_t)(it + 2) * 4096, sK0 + 2 * 4096);
    stage(gV + (size_t)(it + 2) * 4096, sV0 + 2 * 4096);
    QK(sK0, it, pf);
    PV(sV0, pf);
    // body it+1 (buf 1), stage tile it+3 -> buf 0
    sync4();
    stage(gK + (size_t)(it + 3) * 4096, sK0);
    stage(gV + (size_t)(it + 3) * 4096, sV0);
    QK(sK0 + 4096, it + 1, pf);
    PV(sV0 + 4096, pf);
    // body it+2 (buf 2), stage tile it+4 -> buf 1
    sync4();
    stage(gK + (size_t)(it + 4) * 4096, sK0 + 4096);
    stage(gV + (size_t)(it + 4) * 4096, sV0 + 4096);
    QK(sK0 + 2 * 4096, it + 2, pf);
    PV(sV0 + 2 * 4096, pf);
  }

  // peeled tails: it = 30 (buf 0, no stage), it = 31 (buf 1, no stage)
  sync4();                      // tile 30 (staged 2 bodies ago) complete
  QK(sK0, 30, pf);
  PV(sV0, pf);
  sync0();                      // tile 31 complete
  QK(sK0 + 4096, 31, pf);
  PV(sV0 + 4096, pf);

  // ---- normalize & store (no cross-wave combine needed)
#pragma unroll
  for (int tt = 0; tt < 2; ++tt) {
    const float lv = __shfl(lacc[tt][0], ln, 64);   // row0 (q=0) broadcast
    const float inv = 1.0f / lv;
    const int t = t0w + tt * 16 + ln;
#pragma unroll
    for (int dt = 0; dt < 4; ++dt) {
      f32x4 o = Oacc[dt][tt];
      ushort4 pk;
      pk.x = f2bf(o[0] * inv);
      pk.y = f2bf(o[1] * inv);
      pk.z = f2bf(o[2] * inv);
      pk.w = f2bf(o[3] * inv);
      *(ushort4*)(Ob + ((size_t)b * T_ + t) * C_ + h * D_ + dt * 16 + q * 4) = pk;
    }
  }
}

// ---------------------------------------------------------------- out GEMM
__global__ __launch_bounds__(256)
void gemm_out(const unsigned short* __restrict__ Ob,
              const unsigned short* __restrict__ W2,
              const float* __restrict__ bout,
              float* __restrict__ out) {
  __shared__ unsigned short sA[2][128 * 32];
  __shared__ unsigned short sB[2][128 * 32];

  const int b   = blockIdx.z;
  const int o0  = blockIdx.y * 128;
  const int t0  = blockIdx.x * 128;
  const int tid = threadIdx.x;
  const int wave = tid >> 6, lane = tid & 63;
  const int q = lane >> 4, ln = lane & 15;
  const int tw = wave >> 1, ow = wave & 1;

  const unsigned short* Bo = Ob + (size_t)b * T_ * C_;
  const int srow = lane >> 2;
  const int scol = (lane & 3) * 8;

  const f32x4 ZERO = {0.f, 0.f, 0.f, 0.f};
  f32x4 acc[4][4];
#pragma unroll
  for (int mi = 0; mi < 4; ++mi)
#pragma unroll
    for (int ni = 0; ni < 4; ++ni) acc[mi][ni] = ZERO;

#pragma unroll
  for (int j = 0; j < 2; ++j) {
    const int chunk = wave * 2 + j;
    const int row = chunk * 16 + srow;
    async16(W2 + (size_t)(o0 + row) * C_ + scol, &sA[0][chunk * 512]);
    async16(Bo + (size_t)(t0 + row) * C_ + scol, &sB[0][chunk * 512]);
  }

  for (int i = 0; i < 24; ++i) {
    const int buf = i & 1;
    __syncthreads();
    if (i < 23) {
      const int k0 = (i + 1) * 32;
#pragma unroll
      for (int j = 0; j < 2; ++j) {
        const int chunk = wave * 2 + j;
        const int row = chunk * 16 + srow;
        async16(W2 + (size_t)(o0 + row) * C_ + k0 + scol, &sA[buf ^ 1][chunk * 512]);
        async16(Bo + (size_t)(t0 + row) * C_ + k0 + scol, &sB[buf ^ 1][chunk * 512]);
      }
    }

    bf16x8 aF[4], bF[4];
#pragma unroll
    for (int mi = 0; mi < 4; ++mi)
      aF[mi] = *(const bf16x8*)(&sA[buf][(tw * 64 + mi * 16 + ln) * 32 + q * 8]);
#pragma unroll
    for (int ni = 0; ni < 4; ++ni)
      bF[ni] = *(const bf16x8*)(&sB[buf][(ow * 64 + ni * 16 + ln) * 32 + q * 8]);
#pragma unroll
    for (int mi = 0; mi < 4; ++mi)
#pragma unroll
      for (int ni = 0; ni < 4; ++ni)
        acc[mi][ni] = __builtin_amdgcn_mfma_f32_16x16x32_bf16(aF[mi], bF[ni], acc[mi][ni], 0, 0, 0);
  }

#pragma unroll
  for (int mi = 0; mi < 4; ++mi) {
    const int ob = o0 + tw * 64 + mi * 16 + q * 4;
#pragma unroll
    for (int ni = 0; ni < 4; ++ni) {
      const int t = t0 + ow * 64 + ni * 16 + ln;
      f32x4 v = acc[mi][ni];
#pragma unroll
      for (int r = 0; r < 4; ++r)
        out[((size_t)b * C_ + ob + r) * T_ + t] = v[r] + bout[ob + r];
    }
  }
}

// ---------------------------------------------------------------- launch

extern "C" void kernel_launch(void* const* d_in, const int* in_sizes, int n_in,
                              void* d_out, int out_size, void* d_ws, size_t ws_size,
                              hipStream_t stream) {
  (void)in_sizes; (void)n_in; (void)out_size; (void)ws_size;
  const float* x    = (const float*)d_in[0];
  const int*   mask = (const int*)d_in[1];
  const float* Wqkv = (const float*)d_in[2];
  const float* bqkv = (const float*)d_in[3];
  const float* Wout = (const float*)d_in[4];
  const float* bout = (const float*)d_in[5];
  float* out = (float*)d_out;

  const size_t szHead = (size_t)B_ * H_ * T_ * D_;   // 6291456 elems
  const size_t szBTC  = (size_t)B_ * T_ * C_;        // 6291456 elems
  unsigned short* Qb  = (unsigned short*)d_ws;
  unsigned short* Kb  = Qb + szHead;
  unsigned short* Vb  = Kb + szHead;
  unsigned short* Ob  = Vb + szHead;
  unsigned short* xT  = Ob + szBTC;
  unsigned short* W1b = xT + szBTC;
  unsigned short* W2b = W1b + (size_t)O3_ * C_;
  float* mbias        = (float*)(W2b + (size_t)C_ * C_);

  cvt_f32_bf16<<<dim3((O3_ * C_ / 4 + 255) / 256), 256, 0, stream>>>(Wqkv, W1b, O3_ * C_ / 4);
  cvt_f32_bf16<<<dim3((C_ * C_ / 4 + 255) / 256), 256, 0, stream>>>(Wout, W2b, C_ * C_ / 4);
  make_bias<<<dim3((B_ * T_ + 255) / 256), 256, 0, stream>>>(mask, mbias, B_ * T_);
  transpose_x<<<dim3(T_ / 32, C_ / 32, B_), 256, 0, stream>>>(x, xT);
  gemm_qkv<<<dim3(T_ / 128, O3_ / 128, B_), 256, 0, stream>>>(xT, W1b, bqkv, Qb, Kb, Vb);
  attn<<<dim3(768), 256, 0, stream>>>(Qb, Kb, Vb, mbias, Ob);
  gemm_out<<<dim3(T_ / 128, C_ / 128, B_), 256, 0, stream>>>(Ob, W2b, bout, out);
}

// Round 6
// 225.052 us; speedup vs baseline: 1.0433x; 1.0127x over previous
//
#include <hip/hip_runtime.h>
#include <hip/hip_bf16.h>
#include <stdint.h>

#define B_   4
#define C_   768
#define T_   2048
#define H_   12
#define D_   64
#define O3_  2304

typedef __attribute__((ext_vector_type(4))) float f32x4;
typedef __attribute__((ext_vector_type(8))) short bf16x8;

__device__ __forceinline__ unsigned short f2bf(float f) {
  union { float f; unsigned int u; } v; v.f = f;
  unsigned int r = v.u + 0x7fffu + ((v.u >> 16) & 1u);
  return (unsigned short)(r >> 16);
}

__device__ __forceinline__ unsigned int pack2bf(float a, float b) {
  __hip_bfloat162 h2 = __float22bfloat162_rn(make_float2(a, b));
  union { __hip_bfloat162 h; unsigned int u; } cv; cv.h = h2;
  return cv.u;
}

__device__ __forceinline__ float fexp2(float x) {
#if __has_builtin(__builtin_amdgcn_exp2f)
  return __builtin_amdgcn_exp2f(x);
#else
  return exp2f(x);
#endif
}

// async global->LDS, 16B per lane; LDS dest = wave-uniform base + lane*16.
__device__ __forceinline__ void async16(const void* g, void* lds) {
#if __has_builtin(__builtin_amdgcn_global_load_lds)
  __builtin_amdgcn_global_load_lds((const __attribute__((address_space(1))) void*)g,
                                   (__attribute__((address_space(3))) void*)lds, 16, 0, 0);
#else
  int lane = threadIdx.x & 63;
  *((uint4*)((char*)lds + lane * 16)) = *((const uint4*)g);
#endif
}

// ---------------------------------------------------------------- prep kernels

__global__ void cvt_f32_bf16(const float* __restrict__ in,
                             unsigned short* __restrict__ out, int n4) {
  int i = blockIdx.x * 256 + threadIdx.x;
  if (i < n4) {
    float4 f = ((const float4*)in)[i];
    ushort4 o;
    o.x = f2bf(f.x); o.y = f2bf(f.y); o.z = f2bf(f.z); o.w = f2bf(f.w);
    ((ushort4*)out)[i] = o;
  }
}

// mask (B,1,1,T) int -> additive bias in exp2 domain
__global__ void make_bias(const int* __restrict__ mask, float* __restrict__ mbias, int n) {
  int i = blockIdx.x * 256 + threadIdx.x;
  if (i < n) mbias[i] = (mask[i] == 0) ? -14426.950408f : 0.0f;
}

// x[b][c][t] fp32 -> xT[b][t][c] bf16
__global__ void transpose_x(const float* __restrict__ x,
                            unsigned short* __restrict__ xT) {
  __shared__ unsigned short tile[32][33];
  int b = blockIdx.z;
  int c0 = blockIdx.y * 32;
  int t0 = blockIdx.x * 32;
  int tid = threadIdx.x;
  {
    int cl = tid >> 3;
    int tl = (tid & 7) * 4;
    float4 f = *(const float4*)(x + ((size_t)b * C_ + c0 + cl) * T_ + t0 + tl);
    tile[tl + 0][cl] = f2bf(f.x);
    tile[tl + 1][cl] = f2bf(f.y);
    tile[tl + 2][cl] = f2bf(f.z);
    tile[tl + 3][cl] = f2bf(f.w);
  }
  __syncthreads();
  {
    int tl = tid >> 3;
    int cl = (tid & 7) * 4;
    ushort4 o;
    o.x = tile[tl][cl + 0]; o.y = tile[tl][cl + 1];
    o.z = tile[tl][cl + 2]; o.w = tile[tl][cl + 3];
    *(ushort4*)(xT + ((size_t)b * T_ + t0 + tl) * C_ + c0 + cl) = o;
  }
}

// ---------------------------------------------------------------- QKV GEMM
// 128x128 tile, BK=32, TRIPLE-buffered LDS with counted-vmcnt pipeline
// (prefetch depth 2; body boundary = vmcnt(4) lgkmcnt(0) + s_barrier).
// LDS tiles are [128][32] shorts with 16B-chunk swizzle: LDS[r][c] holds
// global chunk c ^ swz(r), swz(r) = (r ^ (r>>2)) & 3 — staged by
// pre-swizzling the global source (global_load_lds dest stays linear),
// read back with the same XOR -> each 8-lane ds_read_b128 phase covers
// all 8 bank spans (conflict-free; was ~4-way).
// Epilogue layouts for attn (unchanged, verified):
//   Qb[bh][t][dd]                      (prescaled by 0.125*log2e)
//   Kb[bh][s][dd]   rows 64 shorts, 16B chunk c=dd>>3 stored at c^(s&7)
//   Vb[bh][tile][dd][64]  64-s tiles, chunk c=si>>3 stored at c^(dd&7)
__global__ __launch_bounds__(256, 3)
void gemm_qkv(const unsigned short* __restrict__ xT,
              const unsigned short* __restrict__ W1,
              const float* __restrict__ bqkv,
              unsigned short* __restrict__ Qb,
              unsigned short* __restrict__ Kb,
              unsigned short* __restrict__ Vb) {
  __shared__ unsigned short sA[3][128 * 32];
  __shared__ unsigned short sB[3][128 * 32];

  const int b   = blockIdx.z;
  const int o0  = blockIdx.y * 128;
  const int t0  = blockIdx.x * 128;
  const int tid = threadIdx.x;
  const int wave = tid >> 6, lane = tid & 63;
  const int q = lane >> 4, ln = lane & 15;
  const int tw = wave >> 1, ow = wave & 1;

  const unsigned short* Ax = xT + (size_t)b * T_ * C_;
  // staging: chunk `wave*2+j` covers rows chunk*16+(lane>>2), 4 16B-chunks/row
  const int srow = lane >> 2;
  const int ssw  = ((lane >> 2) ^ (lane >> 4)) & 3;       // swz(row) for stage
  const int scol = ((lane & 3) ^ ssw) * 8;                 // pre-swizzled src col
  const int rsw  = (ln ^ (ln >> 2)) & 3;                   // swz(row) for read

  const f32x4 ZERO = {0.f, 0.f, 0.f, 0.f};
  f32x4 acc[4][4];
#pragma unroll
  for (int mi = 0; mi < 4; ++mi)
#pragma unroll
    for (int ni = 0; ni < 4; ++ni) acc[mi][ni] = ZERO;

  auto stageA = [&](int ks, int bufi) {
#pragma unroll
    for (int j = 0; j < 2; ++j) {
      const int chunk = wave * 2 + j;
      async16(Ax + (size_t)(t0 + chunk * 16 + srow) * C_ + ks * 32 + scol,
              &sA[bufi][chunk * 512]);
    }
  };
  auto stageB = [&](int ks, int bufi) {
#pragma unroll
    for (int j = 0; j < 2; ++j) {
      const int chunk = wave * 2 + j;
      async16(W1 + (size_t)(o0 + chunk * 16 + srow) * C_ + ks * 32 + scol,
              &sB[bufi][chunk * 512]);
    }
  };
  auto sync4 = [&]() {
    __builtin_amdgcn_sched_barrier(0);
    asm volatile("s_waitcnt vmcnt(4) lgkmcnt(0)" ::: "memory");
    __builtin_amdgcn_s_barrier();
    __builtin_amdgcn_sched_barrier(0);
  };
  auto sync0 = [&]() {
    __builtin_amdgcn_sched_barrier(0);
    asm volatile("s_waitcnt vmcnt(0) lgkmcnt(0)" ::: "memory");
    __builtin_amdgcn_s_barrier();
    __builtin_amdgcn_sched_barrier(0);
  };
  auto compute = [&](int bufi) {
    bf16x8 aF[4], bF[4];
#pragma unroll
    for (int mi = 0; mi < 4; ++mi)
      aF[mi] = *(const bf16x8*)(&sA[bufi][(tw * 64 + mi * 16 + ln) * 32 + ((q ^ rsw) << 3)]);
#pragma unroll
    for (int ni = 0; ni < 4; ++ni)
      bF[ni] = *(const bf16x8*)(&sB[bufi][(ow * 64 + ni * 16 + ln) * 32 + ((q ^ rsw) << 3)]);
#pragma unroll
    for (int mi = 0; mi < 4; ++mi)
#pragma unroll
      for (int ni = 0; ni < 4; ++ni)
        acc[mi][ni] = __builtin_amdgcn_mfma_f32_16x16x32_bf16(aF[mi], bF[ni], acc[mi][ni], 0, 0, 0);
  };

  // prologue: tiles 0,1 in flight (8 loads/wave)
  stageA(0, 0); stageB(0, 0);
  stageA(1, 1); stageB(1, 1);

  // bodies 0..20 (7 groups of 3; body b computes buf b%3, stages tile b+2)
  for (int g = 0; g < 7; ++g) {
    const int t3 = g * 3;
    sync4(); stageA(t3 + 2, 2); stageB(t3 + 2, 2); compute(0);
    sync4(); stageA(t3 + 3, 0); stageB(t3 + 3, 0); compute(1);
    sync4(); stageA(t3 + 4, 1); stageB(t3 + 4, 1); compute(2);
  }
  // body 21 (buf 0, stage tile 23 -> buf 2), 22 (buf 1), 23 (buf 2)
  sync4(); stageA(23, 2); stageB(23, 2); compute(0);
  sync4(); compute(1);
  sync0(); compute(2);

  const float QSCL = 0.125f * 1.44269504f;
#pragma unroll
  for (int ni = 0; ni < 4; ++ni) {
    const int o = o0 + ow * 64 + ni * 16 + ln;
    const float bias = bqkv[o];
    const int which = o / C_;          // uniform per block (768 % 128 == 0)
    const int rem = o - which * C_;
    const int bh = b * H_ + (rem >> 6);
    const int dd = rem & 63;
#pragma unroll
    for (int mi = 0; mi < 4; ++mi) {
      const int tb = t0 + tw * 64 + mi * 16 + q * 4;
      f32x4 v = acc[mi][ni];
      if (which == 0) {
#pragma unroll
        for (int r = 0; r < 4; ++r)
          Qb[((size_t)bh * T_ + tb + r) * D_ + dd] = f2bf((v[r] + bias) * QSCL);
      } else if (which == 1) {
#pragma unroll
        for (int r = 0; r < 4; ++r) {
          const int s = tb + r;
          const int cp = (dd >> 3) ^ (s & 7);
          Kb[((size_t)bh * T_ + s) * 64 + (cp << 3) + (dd & 7)] = f2bf(v[r] + bias);
        }
      } else {
        const int tile = tb >> 6, si = tb & 63;
        const int cp = (si >> 3) ^ (dd & 7);
        ushort4 pk;
        pk.x = f2bf(v[0] + bias);
        pk.y = f2bf(v[1] + bias);
        pk.z = f2bf(v[2] + bias);
        pk.w = f2bf(v[3] + bias);
        *(ushort4*)(Vb + (((size_t)bh * 32 + tile) * 64 + dd) * 64 + (cp << 3) + (si & 7)) = pk;
      }
    }
  }
}

// ---------------------------------------------------------------- attention
// Fixed-max flash (Q prescaled to exp2 domain). One block = (bh, 128 t),
// 4 waves; each wave owns 32 t-cols x FULL s-range (verified r2 structure).
// P stays in registers via permlane32+permlane16 swaps.
// T4 counted-vmcnt pipeline: K/V triple-buffered, prefetch depth 2,
// body boundary = vmcnt(4) lgkmcnt(0) + s_barrier. (verified r5)
__global__ __launch_bounds__(256, 3)
void attn(const unsigned short* __restrict__ Qb,
          const unsigned short* __restrict__ Kb,
          const unsigned short* __restrict__ Vb,
          const float* __restrict__ mbias,
          unsigned short* __restrict__ Ob) {
  __shared__ __align__(16) char smem[49152];
  // [0,24K): sK 3 x 8KB; [24K,48K): sV 3 x 8KB
  unsigned short* sK0 = (unsigned short*)smem;             // + buf*4096 shorts
  unsigned short* sV0 = (unsigned short*)(smem + 24576);

  const int id = blockIdx.x;                  // id = bh + 48*tblk -> XCD = bh%8
  const int bh = id % 48;
  const int tblk = id / 48;
  const int b = bh / H_, h = bh % H_;
  const int tid = threadIdx.x, wave = tid >> 6, lane = tid & 63;
  const int q = lane >> 4, ln = lane & 15;
  const int t0w = tblk * 128 + wave * 32;     // this wave's 32 t-cols

  // Q fragments (B-operand): [tt][kk], t = t0w + tt*16 + ln, k = kk*32+q*8
  bf16x8 Qa[2][2];
#pragma unroll
  for (int tt = 0; tt < 2; ++tt) {
    const unsigned short* qrow = Qb + ((size_t)bh * T_ + t0w + tt * 16 + ln) * D_;
    Qa[tt][0] = *(const bf16x8*)(qrow + q * 8);
    Qa[tt][1] = *(const bf16x8*)(qrow + 32 + q * 8);
  }

  const f32x4 ZERO = {0.f, 0.f, 0.f, 0.f};
  f32x4 Oacc[4][2];   // [dt][tt], O^T C-layout: row=d, col=t
  f32x4 lacc[2];      // [tt], row0 = l
#pragma unroll
  for (int dt = 0; dt < 4; ++dt)
#pragma unroll
    for (int tt = 0; tt < 2; ++tt) Oacc[dt][tt] = ZERO;
#pragma unroll
  for (int tt = 0; tt < 2; ++tt) lacc[tt] = ZERO;

  const short one_s = (ln == 0) ? (short)0x3F80 : (short)0;
  bf16x8 ones;
#pragma unroll
  for (int j = 0; j < 8; ++j) ones[j] = one_s;

  const unsigned short* gK = Kb + (size_t)bh * T_ * 64;
  const unsigned short* gV = Vb + (size_t)bh * 32 * 4096;
  const float* mb = mbias + b * T_;

  // pre-collapse mask to one bit per 64-s tile (no vmem inside the hot loop)
  unsigned int maskbits = 0;
  for (int t2 = 0; t2 < 32; ++t2)
    if (__ballot(mb[t2 * 64 + lane] != 0.0f) != 0ull) maskbits |= (1u << t2);

  // stage one 8KB tile (64 rows x 64 shorts): 8 chunks of 1KB, 2 per wave
  auto stage = [&](const unsigned short* g, unsigned short* lds) {
#pragma unroll
    for (int j = 0; j < 2; ++j) {
      const int chunk = wave * 2 + j;
      async16(g + chunk * 512 + lane * 8, lds + chunk * 512);
    }
  };

  auto sync4 = [&]() {
    __builtin_amdgcn_sched_barrier(0);
    asm volatile("s_waitcnt vmcnt(4) lgkmcnt(0)" ::: "memory");
    __builtin_amdgcn_s_barrier();
    __builtin_amdgcn_sched_barrier(0);
  };
  auto sync0 = [&]() {
    __builtin_amdgcn_sched_barrier(0);
    asm volatile("s_waitcnt vmcnt(0) lgkmcnt(0)" ::: "memory");
    __builtin_amdgcn_s_barrier();
    __builtin_amdgcn_sched_barrier(0);
  };

  // QK^T for one 64-s tile; emits P B-fragments (s = kc*32 + q*8 + j, t = ln)
  auto QK = [&](const unsigned short* sKc, int it, bf16x8 pfO[2][2]) {
    const int s0 = it * 64;
    const bool anymask = (maskbits >> it) & 1;
#pragma unroll
    for (int kc = 0; kc < 2; ++kc) {
      bf16x8 kf0[2], kf1[2];
#pragma unroll
      for (int sb = 0; sb < 2; ++sb) {
        const unsigned short* krow = sKc + (kc * 32 + sb * 16 + ln) * 64;
        kf0[sb] = *(const bf16x8*)(krow + ((q ^ (ln & 7)) << 3));
        kf1[sb] = *(const bf16x8*)(krow + (((4 + q) ^ (ln & 7)) << 3));
      }
#pragma unroll
      for (int tt = 0; tt < 2; ++tt) {
        f32x4 sc[2];
#pragma unroll
        for (int sb = 0; sb < 2; ++sb) {
          f32x4 p0 = __builtin_amdgcn_mfma_f32_16x16x32_bf16(kf0[sb], Qa[tt][0], ZERO, 0, 0, 0);
          sc[sb]   = __builtin_amdgcn_mfma_f32_16x16x32_bf16(kf1[sb], Qa[tt][1], p0, 0, 0, 0);
          if (anymask) {
            f32x4 bb = *(const f32x4*)(mb + s0 + kc * 32 + sb * 16 + q * 4);
#pragma unroll
            for (int r = 0; r < 4; ++r) sc[sb][r] += bb[r];
          }
        }
        unsigned int A0 = pack2bf(fexp2(sc[0][0]), fexp2(sc[0][1]));
        unsigned int B0 = pack2bf(fexp2(sc[0][2]), fexp2(sc[0][3]));
        unsigned int C0 = pack2bf(fexp2(sc[1][0]), fexp2(sc[1][1]));
        unsigned int E0 = pack2bf(fexp2(sc[1][2]), fexp2(sc[1][3]));
        // swap network: (A0,C0) -> (T0,T2), (B0,E0) -> (T1,T3)
        asm volatile("v_permlane32_swap_b32 %0, %1" : "+v"(A0), "+v"(C0));
        asm volatile("v_permlane16_swap_b32 %0, %1" : "+v"(A0), "+v"(C0));
        asm volatile("v_permlane32_swap_b32 %0, %1" : "+v"(B0), "+v"(E0));
        asm volatile("v_permlane16_swap_b32 %0, %1" : "+v"(B0), "+v"(E0));
        union { bf16x8 v; unsigned int u[4]; } P;
        P.u[0] = A0;  // s = q*8 + {0,1}
        P.u[1] = B0;  // s = q*8 + {2,3}
        P.u[2] = C0;  // s = q*8 + {4,5}
        P.u[3] = E0;  // s = q*8 + {6,7}
        pfO[tt][kc] = P.v;
      }
    }
  };

  // PV for one 64-s tile using prepared P-fragments
  auto PV = [&](const unsigned short* sVc, bf16x8 pfI[2][2]) {
#pragma unroll
    for (int dt = 0; dt < 4; ++dt) {
#pragma unroll
      for (int kc = 0; kc < 2; ++kc) {
        bf16x8 vf = *(const bf16x8*)(sVc + (dt * 16 + ln) * 64 +
                                     (((kc * 4 + q) ^ (ln & 7)) << 3));
#pragma unroll
        for (int tt = 0; tt < 2; ++tt)
          Oacc[dt][tt] = __builtin_amdgcn_mfma_f32_16x16x32_bf16(vf, pfI[tt][kc], Oacc[dt][tt], 0, 0, 0);
      }
    }
#pragma unroll
    for (int kc = 0; kc < 2; ++kc)
#pragma unroll
      for (int tt = 0; tt < 2; ++tt)
        lacc[tt] = __builtin_amdgcn_mfma_f32_16x16x32_bf16(ones, pfI[tt][kc], lacc[tt], 0, 0, 0);
  };

  bf16x8 pf[2][2];

  // prologue: stage tiles 0 and 1 (8 loads outstanding per wave)
  stage(gK, sK0);
  stage(gV, sV0);
  stage(gK + 4096, sK0 + 4096);
  stage(gV + 4096, sV0 + 4096);

  // main loop: 10 triple-bodies cover it = 0..29; buffer index = it%3 static
  for (int ith = 0; ith < 10; ++ith) {
    const int it = ith * 3;
    // body it (buf 0), stage tile it+2 -> buf 2
    sync4();
    stage(gK + (size_t)(it + 2) * 4096, sK0 + 2 * 4096);
    stage(gV + (size_t)(it + 2) * 4096, sV0 + 2 * 4096);
    QK(sK0, it, pf);
    PV(sV0, pf);
    // body it+1 (buf 1), stage tile it+3 -> buf 0
    sync4();
    stage(gK + (size_t)(it + 3) * 4096, sK0);
    stage(gV + (size_t)(it + 3) * 4096, sV0);
    QK(sK0 + 4096, it + 1, pf);
    PV(sV0 + 4096, pf);
    // body it+2 (buf 2), stage tile it+4 -> buf 1
    sync4();
    stage(gK + (size_t)(it + 4) * 4096, sK0 + 4096);
    stage(gV + (size_t)(it + 4) * 4096, sV0 + 4096);
    QK(sK0 + 2 * 4096, it + 2, pf);
    PV(sV0 + 2 * 4096, pf);
  }

  // peeled tails: it = 30 (buf 0, no stage), it = 31 (buf 1, no stage)
  sync4();                      // tile 30 (staged 2 bodies ago) complete
  QK(sK0, 30, pf);
  PV(sV0, pf);
  sync0();                      // tile 31 complete
  QK(sK0 + 4096, 31, pf);
  PV(sV0 + 4096, pf);

  // ---- normalize & store (no cross-wave combine needed)
#pragma unroll
  for (int tt = 0; tt < 2; ++tt) {
    const float lv = __shfl(lacc[tt][0], ln, 64);   // row0 (q=0) broadcast
    const float inv = 1.0f / lv;
    const int t = t0w + tt * 16 + ln;
#pragma unroll
    for (int dt = 0; dt < 4; ++dt) {
      f32x4 o = Oacc[dt][tt];
      ushort4 pk;
      pk.x = f2bf(o[0] * inv);
      pk.y = f2bf(o[1] * inv);
      pk.z = f2bf(o[2] * inv);
      pk.w = f2bf(o[3] * inv);
      *(ushort4*)(Ob + ((size_t)b * T_ + t) * C_ + h * D_ + dt * 16 + q * 4) = pk;
    }
  }
}

// ---------------------------------------------------------------- out GEMM
// Same triple-buffer counted-vmcnt + chunk-swizzle structure as gemm_qkv.
__global__ __launch_bounds__(256, 3)
void gemm_out(const unsigned short* __restrict__ Ob,
              const unsigned short* __restrict__ W2,
              const float* __restrict__ bout,
              float* __restrict__ out) {
  __shared__ unsigned short sA[3][128 * 32];
  __shared__ unsigned short sB[3][128 * 32];

  const int b   = blockIdx.z;
  const int o0  = blockIdx.y * 128;
  const int t0  = blockIdx.x * 128;
  const int tid = threadIdx.x;
  const int wave = tid >> 6, lane = tid & 63;
  const int q = lane >> 4, ln = lane & 15;
  const int tw = wave >> 1, ow = wave & 1;

  const unsigned short* Bo = Ob + (size_t)b * T_ * C_;
  const int srow = lane >> 2;
  const int ssw  = ((lane >> 2) ^ (lane >> 4)) & 3;
  const int scol = ((lane & 3) ^ ssw) * 8;
  const int rsw  = (ln ^ (ln >> 2)) & 3;

  const f32x4 ZERO = {0.f, 0.f, 0.f, 0.f};
  f32x4 acc[4][4];
#pragma unroll
  for (int mi = 0; mi < 4; ++mi)
#pragma unroll
    for (int ni = 0; ni < 4; ++ni) acc[mi][ni] = ZERO;

  auto stageA = [&](int ks, int bufi) {
#pragma unroll
    for (int j = 0; j < 2; ++j) {
      const int chunk = wave * 2 + j;
      async16(W2 + (size_t)(o0 + chunk * 16 + srow) * C_ + ks * 32 + scol,
              &sA[bufi][chunk * 512]);
    }
  };
  auto stageB = [&](int ks, int bufi) {
#pragma unroll
    for (int j = 0; j < 2; ++j) {
      const int chunk = wave * 2 + j;
      async16(Bo + (size_t)(t0 + chunk * 16 + srow) * C_ + ks * 32 + scol,
              &sB[bufi][chunk * 512]);
    }
  };
  auto sync4 = [&]() {
    __builtin_amdgcn_sched_barrier(0);
    asm volatile("s_waitcnt vmcnt(4) lgkmcnt(0)" ::: "memory");
    __builtin_amdgcn_s_barrier();
    __builtin_amdgcn_sched_barrier(0);
  };
  auto sync0 = [&]() {
    __builtin_amdgcn_sched_barrier(0);
    asm volatile("s_waitcnt vmcnt(0) lgkmcnt(0)" ::: "memory");
    __builtin_amdgcn_s_barrier();
    __builtin_amdgcn_sched_barrier(0);
  };
  auto compute = [&](int bufi) {
    bf16x8 aF[4], bF[4];
#pragma unroll
    for (int mi = 0; mi < 4; ++mi)
      aF[mi] = *(const bf16x8*)(&sA[bufi][(tw * 64 + mi * 16 + ln) * 32 + ((q ^ rsw) << 3)]);
#pragma unroll
    for (int ni = 0; ni < 4; ++ni)
      bF[ni] = *(const bf16x8*)(&sB[bufi][(ow * 64 + ni * 16 + ln) * 32 + ((q ^ rsw) << 3)]);
#pragma unroll
    for (int mi = 0; mi < 4; ++mi)
#pragma unroll
      for (int ni = 0; ni < 4; ++ni)
        acc[mi][ni] = __builtin_amdgcn_mfma_f32_16x16x32_bf16(aF[mi], bF[ni], acc[mi][ni], 0, 0, 0);
  };

  stageA(0, 0); stageB(0, 0);
  stageA(1, 1); stageB(1, 1);

  for (int g = 0; g < 7; ++g) {
    const int t3 = g * 3;
    sync4(); stageA(t3 + 2, 2); stageB(t3 + 2, 2); compute(0);
    sync4(); stageA(t3 + 3, 0); stageB(t3 + 3, 0); compute(1);
    sync4(); stageA(t3 + 4, 1); stageB(t3 + 4, 1); compute(2);
  }
  sync4(); stageA(23, 2); stageB(23, 2); compute(0);
  sync4(); compute(1);
  sync0(); compute(2);

#pragma unroll
  for (int mi = 0; mi < 4; ++mi) {
    const int ob = o0 + tw * 64 + mi * 16 + q * 4;
#pragma unroll
    for (int ni = 0; ni < 4; ++ni) {
      const int t = t0 + ow * 64 + ni * 16 + ln;
      f32x4 v = acc[mi][ni];
#pragma unroll
      for (int r = 0; r < 4; ++r)
        out[((size_t)b * C_ + ob + r) * T_ + t] = v[r] + bout[ob + r];
    }
  }
}

// ---------------------------------------------------------------- launch

extern "C" void kernel_launch(void* const* d_in, const int* in_sizes, int n_in,
                              void* d_out, int out_size, void* d_ws, size_t ws_size,
                              hipStream_t stream) {
  (void)in_sizes; (void)n_in; (void)out_size; (void)ws_size;
  const float* x    = (const float*)d_in[0];
  const int*   mask = (const int*)d_in[1];
  const float* Wqkv = (const float*)d_in[2];
  const float* bqkv = (const float*)d_in[3];
  const float* Wout = (const float*)d_in[4];
  const float* bout = (const float*)d_in[5];
  float* out = (float*)d_out;

  const size_t szHead = (size_t)B_ * H_ * T_ * D_;   // 6291456 elems
  const size_t szBTC  = (size_t)B_ * T_ * C_;        // 6291456 elems
  unsigned short* Qb  = (unsigned short*)d_ws;
  unsigned short* Kb  = Qb + szHead;
  unsigned short* Vb  = Kb + szHead;
  unsigned short* Ob  = Vb + szHead;
  unsigned short* xT  = Ob + szBTC;
  unsigned short* W1b = xT + szBTC;
  unsigned short* W2b = W1b + (size_t)O3_ * C_;
  float* mbias        = (float*)(W2b + (size_t)C_ * C_);

  cvt_f32_bf16<<<dim3((O3_ * C_ / 4 + 255) / 256), 256, 0, stream>>>(Wqkv, W1b, O3_ * C_ / 4);
  cvt_f32_bf16<<<dim3((C_ * C_ / 4 + 255) / 256), 256, 0, stream>>>(Wout, W2b, C_ * C_ / 4);
  make_bias<<<dim3((B_ * T_ + 255) / 256), 256, 0, stream>>>(mask, mbias, B_ * T_);
  transpose_x<<<dim3(T_ / 32, C_ / 32, B_), 256, 0, stream>>>(x, xT);
  gemm_qkv<<<dim3(T_ / 128, O3_ / 128, B_), 256, 0, stream>>>(xT, W1b, bqkv, Qb, Kb, Vb);
  attn<<<dim3(768), 256, 0, stream>>>(Qb, Kb, Vb, mbias, Ob);
  gemm_out<<<dim3(T_ / 128, C_ / 128, B_), 256, 0, stream>>>(Ob, W2b, bout, out);
}